// Round 11
// baseline (1911.354 us; speedup 1.0000x reference)
//
#include <hip/hip_runtime.h>
#include <math.h>

#define B 2048
#define H 256
#define INDIM 320
#define NOPS 1883
#define STEPS 20

typedef _Float16 f16;
typedef _Float16 f16x4 __attribute__((ext_vector_type(4)));
typedef _Float16 f16x8 __attribute__((ext_vector_type(8)));
typedef float f32x4 __attribute__((ext_vector_type(4)));
typedef unsigned long long u64;

// XOR swizzle: 4 16B-slots per 64B (32-f16) row; bijective involution per row.
#define SWZ(r, s) ((s) ^ ((r) & 3) ^ (((r) >> 2) & 1))

// direct global->LDS 16B copy (LDS dest must be linear in lane order)
#define GLDS(src, dst) __builtin_amdgcn_global_load_lds( \
    (__attribute__((address_space(1))) void*)(src), \
    (__attribute__((address_space(3))) void*)(dst), 16, 0, 0)

#define S1 (1.0f / 1024.0f)
#define S2 (1.0f / 1048576.0f)

__device__ __forceinline__ void split3(float f, f16& c0, f16& c1, f16& c2) {
    c0 = (f16)f;
    float r1 = f - (float)c0;
    c1 = (f16)(r1 * 1024.0f);
    float r2 = r1 - (float)c1 * S1;
    c2 = (f16)(r2 * 1048576.0f);
}

// ---------------- init ----------------
__global__ __launch_bounds__(256) void init_kernel(const float* __restrict__ geo,
                                                   const float* __restrict__ sem,
                                                   f16* __restrict__ x0, f16* __restrict__ x1,
                                                   f16* __restrict__ x2,
                                                   float* __restrict__ h0f, float* __restrict__ h1f,
                                                   f16* __restrict__ h0c0, f16* __restrict__ h0c1,
                                                   f16* __restrict__ h0c2,
                                                   f16* __restrict__ h1c0, f16* __restrict__ h1c1,
                                                   f16* __restrict__ h1c2,
                                                   float* __restrict__ hsq, u64* __restrict__ amax) {
    int i = blockIdx.x * blockDim.x + threadIdx.x;
    if (i < B * INDIM) {
        int b = i / INDIM, c = i % INDIM;
        float f = (c < 256) ? geo[b * 256 + c] : sem[b * 64 + (c - 256)];
        f16 a, bb, cc;
        split3(f, a, bb, cc);
        x0[i] = a; x1[i] = bb; x2[i] = cc;
    }
    if (i < B * H) {
        h0f[i] = 0.0f; h1f[i] = 0.0f;
        h0c0[i] = (f16)0.0f; h0c1[i] = (f16)0.0f; h0c2[i] = (f16)0.0f;
        h1c0[i] = (f16)0.0f; h1c1[i] = (f16)0.0f; h1c2[i] = (f16)0.0f;
    }
    if (i < B) { hsq[i] = 0.0f; amax[i] = 0ull; }
}

// ---------------- generic tiled GEMM C = A * B^T (opp precompute) ----------------
#define BM 64
#define BN 64
#define BK 16
__global__ __launch_bounds__(256) void gemm_tn(const float* __restrict__ A,
                                               const float* __restrict__ Bm,
                                               const float* __restrict__ bias,
                                               float* __restrict__ C,
                                               int M, int N, int K) {
    __shared__ float As[BK][BM];
    __shared__ float Bs[BK][BN];
    int tid = threadIdx.x;
    int bm0 = blockIdx.y * BM;
    int bn0 = blockIdx.x * BN;
    int tx = tid & 15, ty = tid >> 4;
    int lr = tid >> 2;
    int lk = (tid & 3) << 2;

    float acc[4][4];
#pragma unroll
    for (int i = 0; i < 4; ++i)
#pragma unroll
        for (int j = 0; j < 4; ++j) acc[i][j] = 0.0f;

    for (int k0 = 0; k0 < K; k0 += BK) {
        {
            int gr = bm0 + lr;
            float4 v = make_float4(0.f, 0.f, 0.f, 0.f);
            if (gr < M) v = *(const float4*)(A + (size_t)gr * K + k0 + lk);
            As[lk + 0][lr] = v.x; As[lk + 1][lr] = v.y;
            As[lk + 2][lr] = v.z; As[lk + 3][lr] = v.w;
        }
        {
            int gn = bn0 + lr;
            float4 v = make_float4(0.f, 0.f, 0.f, 0.f);
            if (gn < N) v = *(const float4*)(Bm + (size_t)gn * K + k0 + lk);
            Bs[lk + 0][lr] = v.x; Bs[lk + 1][lr] = v.y;
            Bs[lk + 2][lr] = v.z; Bs[lk + 3][lr] = v.w;
        }
        __syncthreads();
#pragma unroll
        for (int k = 0; k < BK; ++k) {
            float a[4], b[4];
#pragma unroll
            for (int i = 0; i < 4; ++i) a[i] = As[k][ty * 4 + i];
#pragma unroll
            for (int j = 0; j < 4; ++j) b[j] = Bs[k][tx * 4 + j];
#pragma unroll
            for (int i = 0; i < 4; ++i)
#pragma unroll
                for (int j = 0; j < 4; ++j) acc[i][j] = fmaf(a[i], b[j], acc[i][j]);
        }
        __syncthreads();
    }
#pragma unroll
    for (int i = 0; i < 4; ++i) {
        int gr = bm0 + ty * 4 + i;
        if (gr >= M) continue;
#pragma unroll
        for (int j = 0; j < 4; ++j) {
            int gc = bn0 + tx * 4 + j;
            if (gc < N) C[(size_t)gr * N + gc] = acc[i][j] + (bias ? bias[gc] : 0.0f);
        }
    }
}

// ---------------- tiled GEMM C = A * B — Wc precompute ----------------
__global__ __launch_bounds__(256) void gemm_nn(const float* __restrict__ A,
                                               const float* __restrict__ Bm,
                                               float* __restrict__ C,
                                               int M, int N, int K) {
    __shared__ float As[BK][BM];
    __shared__ float Bs[BK][BN];
    int tid = threadIdx.x;
    int bm0 = blockIdx.y * BM;
    int bn0 = blockIdx.x * BN;
    int tx = tid & 15, ty = tid >> 4;
    int lr = tid >> 2;
    int lk = (tid & 3) << 2;

    float acc[4][4];
#pragma unroll
    for (int i = 0; i < 4; ++i)
#pragma unroll
        for (int j = 0; j < 4; ++j) acc[i][j] = 0.0f;

    for (int k0 = 0; k0 < K; k0 += BK) {
        {
            int gr = bm0 + lr;
            float4 v = make_float4(0.f, 0.f, 0.f, 0.f);
            if (gr < M) v = *(const float4*)(A + (size_t)gr * K + k0 + lk);
            As[lk + 0][lr] = v.x; As[lk + 1][lr] = v.y;
            As[lk + 2][lr] = v.z; As[lk + 3][lr] = v.w;
        }
        {
            int kk = tid >> 4;
            int n4 = (tid & 15) << 2;
            float4 v = *(const float4*)(Bm + (size_t)(k0 + kk) * N + bn0 + n4);
            Bs[kk][n4 + 0] = v.x; Bs[kk][n4 + 1] = v.y;
            Bs[kk][n4 + 2] = v.z; Bs[kk][n4 + 3] = v.w;
        }
        __syncthreads();
#pragma unroll
        for (int k = 0; k < BK; ++k) {
            float a[4], b[4];
#pragma unroll
            for (int i = 0; i < 4; ++i) a[i] = As[k][ty * 4 + i];
#pragma unroll
            for (int j = 0; j < 4; ++j) b[j] = Bs[k][tx * 4 + j];
#pragma unroll
            for (int i = 0; i < 4; ++i)
#pragma unroll
                for (int j = 0; j < 4; ++j) acc[i][j] = fmaf(a[i], b[j], acc[i][j]);
        }
        __syncthreads();
    }
#pragma unroll
    for (int i = 0; i < 4; ++i) {
        int gr = bm0 + ty * 4 + i;
        if (gr >= M) continue;
#pragma unroll
        for (int j = 0; j < 4; ++j) {
            int gc = bn0 + tx * 4 + j;
            if (gc < N) C[(size_t)gr * N + gc] = acc[i][j];
        }
    }
}

// ---------------- bihc[g] = b_ih0[g] + dot(Wi0[g,:320], bp) ----------------
__global__ __launch_bounds__(256) void rowdot_bias(const float* __restrict__ A,
                                                   const float* __restrict__ v,
                                                   const float* __restrict__ b0,
                                                   float* __restrict__ outb) {
    int row = blockIdx.x * 4 + (threadIdx.x >> 6);
    int lane = threadIdx.x & 63;
    if (row >= 768) return;
    float s = 0.0f;
    for (int j = lane; j < 320; j += 64) s = fmaf(A[(size_t)row * 320 + j], v[j], s);
#pragma unroll
    for (int off = 32; off > 0; off >>= 1) s += __shfl_down(s, off);
    if (lane == 0) outb[row] = b0[row] + s;
}

// ---------------- fp32 -> fp16 hi/lo double split + optional row sumsq -----
__global__ __launch_bounds__(256) void cvt_rows(const float* __restrict__ A, int rows, int cols,
                                                f16* __restrict__ hi, f16* __restrict__ lo,
                                                float* __restrict__ sq) {
    int row = blockIdx.x * 4 + (threadIdx.x >> 6);
    int lane = threadIdx.x & 63;
    if (row >= rows) return;
    const float* src = A + (size_t)row * cols;
    float s = 0.0f;
    for (int c0 = 0; c0 < cols; c0 += 256) {
        int idx = c0 + lane * 4;
        if (idx < cols) {
            float4 v = *(const float4*)(src + idx);
            float vv[4] = {v.x, v.y, v.z, v.w};
            f16x4 h, l;
#pragma unroll
            for (int j = 0; j < 4; ++j) {
                float f = vv[j];
                f16 hv = (f16)f;
                h[j] = hv;
                l[j] = (f16)((f - (float)hv) * 1024.0f);
                s = fmaf(f, f, s);
            }
            *(f16x4*)(hi + (size_t)row * cols + idx) = h;
            *(f16x4*)(lo + (size_t)row * cols + idx) = l;
        }
    }
    if (sq) {
#pragma unroll
        for (int off = 32; off > 0; off >>= 1) s += __shfl_down(s, off);
        if (lane == 0) sq[row] = s;
    }
}

// ---------------- fp32 -> fp16 triple split ----------------
__global__ __launch_bounds__(256) void cvt3_rows(const float* __restrict__ A, int rows, int cols,
                                                 f16* __restrict__ o0, f16* __restrict__ o1,
                                                 f16* __restrict__ o2) {
    int row = blockIdx.x * 4 + (threadIdx.x >> 6);
    int lane = threadIdx.x & 63;
    if (row >= rows) return;
    const float* src = A + (size_t)row * cols;
    for (int c0 = 0; c0 < cols; c0 += 256) {
        int idx = c0 + lane * 4;
        if (idx < cols) {
            float4 v = *(const float4*)(src + idx);
            float vv[4] = {v.x, v.y, v.z, v.w};
            f16x4 a, b, c;
#pragma unroll
            for (int j = 0; j < 4; ++j) {
                f16 p, q, r;
                split3(vv[j], p, q, r);
                a[j] = p; b[j] = q; c[j] = r;
            }
            *(f16x4*)(o0 + (size_t)row * cols + idx) = a;
            *(f16x4*)(o1 + (size_t)row * cols + idx) = b;
            *(f16x4*)(o2 + (size_t)row * cols + idx) = c;
        }
    }
}

// ---------------- MFMA inner, 32m x 16c tile (2 waves: mfrag 0/1) ----------------
// sA: [third 3][kslot 2][32 rows][32]  (strides 2048 / 1024 / 32)
// sW: [third 3][kslot 2][48 rows][32]  (strides 3072 / 1536 / 32), row = gate*16 + col
__device__ __forceinline__ void gru_mfma_tile(
    const f16* sA, const f16* sW, int lane, int mfrag,
    f32x4* acc, f32x4* accx, f32x4* accy) {
#pragma unroll
    for (int kslot = 0; kslot < 2; ++kslot) {
        int ar = mfrag * 16 + (lane & 15);
        int asl = SWZ(ar, lane >> 4);
        f16x8 a0 = *(const f16x8*)&sA[kslot * 1024 + ar * 32 + asl * 8];
        f16x8 a1 = *(const f16x8*)&sA[2048 + kslot * 1024 + ar * 32 + asl * 8];
        f16x8 a2 = *(const f16x8*)&sA[4096 + kslot * 1024 + ar * 32 + asl * 8];
#pragma unroll
        for (int g = 0; g < 3; ++g) {
            int br_ = g * 16 + (lane & 15);
            int bsl = SWZ(br_, lane >> 4);
            f16x8 b0 = *(const f16x8*)&sW[kslot * 1536 + br_ * 32 + bsl * 8];
            f16x8 b1 = *(const f16x8*)&sW[3072 + kslot * 1536 + br_ * 32 + bsl * 8];
            f16x8 b2 = *(const f16x8*)&sW[6144 + kslot * 1536 + br_ * 32 + bsl * 8];
            acc[g]  = __builtin_amdgcn_mfma_f32_16x16x32_f16(a0, b0, acc[g], 0, 0, 0);
            accx[g] = __builtin_amdgcn_mfma_f32_16x16x32_f16(a0, b1, accx[g], 0, 0, 0);
            accx[g] = __builtin_amdgcn_mfma_f32_16x16x32_f16(a1, b0, accx[g], 0, 0, 0);
            accy[g] = __builtin_amdgcn_mfma_f32_16x16x32_f16(a0, b2, accy[g], 0, 0, 0);
            accy[g] = __builtin_amdgcn_mfma_f32_16x16x32_f16(a1, b1, accy[g], 0, 0, 0);
            accy[g] = __builtin_amdgcn_mfma_f32_16x16x32_f16(a2, b0, accy[g], 0, 0, 0);
        }
    }
}

// ---------------- triple-split GRU k-phase; 32x16 tile, 128 thr, gload_lds -------------
// A: 3x2x32x4 = 768 float4 (6 passes of 128); W: 3x2x48x4 = 1152 float4 (9 passes).
__device__ __forceinline__ void gru_phase3(
    const f16* __restrict__ A0, const f16* __restrict__ A1, const f16* __restrict__ A2,
    const f16* __restrict__ W0, const f16* __restrict__ W1, const f16* __restrict__ W2,
    int K, int m0, int c0, int tid, int lane, int mfrag,
    f32x4* acc, f32x4* accx, f32x4* accy, f16* sA, f16* sW) {
    for (int k0 = 0; k0 < K; k0 += 64) {
#pragma unroll
        for (int it = 0; it < 6; ++it) {
            int idx = tid + 128 * it;
            int third = idx >> 8, rem = idx & 255;
            int kslot = rem >> 7, within = rem & 127;
            int row = within >> 2, slot = within & 3;
            const f16* src = (third == 0 ? A0 : third == 1 ? A1 : A2)
                             + (size_t)(m0 + row) * K + k0 + kslot * 32 + SWZ(row, slot) * 8;
            GLDS(src, &sA[idx * 8]);
        }
#pragma unroll
        for (int it = 0; it < 9; ++it) {
            int idx = tid + 128 * it;
            int third = idx / 384;
            int rem = idx - third * 384;
            int kslot = rem / 192;
            int within = rem - kslot * 192;
            int row = within >> 2, slot = within & 3;
            int wr = ((row >> 4) << 8) + c0 + (row & 15);
            const f16* src = (third == 0 ? W0 : third == 1 ? W1 : W2)
                             + (size_t)wr * K + k0 + kslot * 32 + SWZ(row, slot) * 8;
            GLDS(src, &sW[idx * 8]);
        }
        __syncthreads();
        gru_mfma_tile(sA, sW, lane, mfrag, acc, accx, accy);
        __syncthreads();
    }
}

// A = concat(H1[256], emb[sel][256]); W stride 512. 32x16 tile.
__device__ __forceinline__ void gru_phase3_f(
    const f16* __restrict__ H10, const f16* __restrict__ H11, const f16* __restrict__ H12,
    const f16* __restrict__ E0, const f16* __restrict__ E1, const f16* __restrict__ E2,
    const unsigned* __restrict__ sSel,
    const f16* __restrict__ W0, const f16* __restrict__ W1, const f16* __restrict__ W2,
    int m0, int c0, int tid, int lane, int mfrag,
    f32x4* acc, f32x4* accx, f32x4* accy, f16* sA, f16* sW) {
    for (int k0 = 0; k0 < 512; k0 += 64) {
#pragma unroll
        for (int it = 0; it < 6; ++it) {
            int idx = tid + 128 * it;
            int third = idx >> 8, rem = idx & 255;
            int kslot = rem >> 7, within = rem & 127;
            int row = within >> 2, slot = within & 3;
            int keff = k0 + kslot * 32;
            const f16* src;
            if (keff < 256) {
                const f16* base = (third == 0 ? H10 : third == 1 ? H11 : H12);
                src = base + (size_t)(m0 + row) * 256 + keff + SWZ(row, slot) * 8;
            } else {
                const f16* base = (third == 0 ? E0 : third == 1 ? E1 : E2);
                src = base + (size_t)sSel[row] * 256 + (keff - 256) + SWZ(row, slot) * 8;
            }
            GLDS(src, &sA[idx * 8]);
        }
#pragma unroll
        for (int it = 0; it < 9; ++it) {
            int idx = tid + 128 * it;
            int third = idx / 384;
            int rem = idx - third * 384;
            int kslot = rem / 192;
            int within = rem - kslot * 192;
            int row = within >> 2, slot = within & 3;
            int wr = ((row >> 4) << 8) + c0 + (row & 15);
            const f16* src = (third == 0 ? W0 : third == 1 ? W1 : W2)
                             + (size_t)wr * 512 + k0 + kslot * 32 + SWZ(row, slot) * 8;
            GLDS(src, &sW[idx * 8]);
        }
        __syncthreads();
        gru_mfma_tile(sA, sW, lane, mfrag, acc, accx, accy);
        __syncthreads();
    }
}

// ---------------- GRU epilogue (32x16) ----------------
__device__ __forceinline__ void gru_epilogue(
    f32x4* acc, f32x4* accx, f32x4* accy, float gi[3][4],
    const float* bih, const float* bhh,
    const float* Hprevf, float* Hnewf,
    f16* O0, f16* O1, f16* O2, float* hsq_acc,
    int m0, int c0, int lane, int mfrag) {
    int c = c0 + (lane & 15);
    float br = bih[c] + bhh[c];
    float bz = bih[256 + c] + bhh[256 + c];
    float bni = bih[512 + c];
    float bnh = bhh[512 + c];
#pragma unroll
    for (int r = 0; r < 4; ++r) {
        int row = m0 + mfrag * 16 + (lane >> 4) * 4 + r;
        float gh_r = acc[0][r] + accx[0][r] * S1 + accy[0][r] * S2;
        float gh_z = acc[1][r] + accx[1][r] * S1 + accy[1][r] * S2;
        float gh_n = acc[2][r] + accx[2][r] * S1 + accy[2][r] * S2;
        float rg = 1.0f / (1.0f + expf(-(gi[0][r] + gh_r + br)));
        float zg = 1.0f / (1.0f + expf(-(gi[1][r] + gh_z + bz)));
        float ng = tanhf(gi[2][r] + bni + rg * (gh_n + bnh));
        float hp = Hprevf[(size_t)row * 256 + c];
        float o = (1.0f - zg) * ng + zg * hp;
        Hnewf[(size_t)row * 256 + c] = o;
        f16 q0, q1, q2;
        split3(o, q0, q1, q2);
        O0[(size_t)row * 256 + c] = q0;
        O1[(size_t)row * 256 + c] = q1;
        O2[(size_t)row * 256 + c] = q2;
        if (hsq_acc) {
            float sq = o * o;
#pragma unroll
            for (int off = 1; off < 16; off <<= 1) sq += __shfl_xor(sq, off);
            if ((lane & 15) == 0) atomicAdd(hsq_acc + row, sq);
        }
    }
}

// ---------------- GRU layer (generic A; t=0 gru0, all gru1). 128 thr, 4 blocks/CU -----
__global__ __launch_bounds__(128, 2) void gru_mfma3(
    const f16* __restrict__ A0, const f16* __restrict__ A1, const f16* __restrict__ A2, int K1,
    const f16* __restrict__ Wi0, const f16* __restrict__ Wi1, const f16* __restrict__ Wi2,
    const f16* __restrict__ P0, const f16* __restrict__ P1, const f16* __restrict__ P2,
    const f16* __restrict__ Wh0, const f16* __restrict__ Wh1, const f16* __restrict__ Wh2,
    const float* __restrict__ bih, const float* __restrict__ bhh,
    const float* __restrict__ Hprevf,
    float* __restrict__ Hnewf,
    f16* __restrict__ O0, f16* __restrict__ O1, f16* __restrict__ O2,
    float* __restrict__ hsq_zero, float* __restrict__ hsq_acc,
    u64* __restrict__ amax_zero) {
    __shared__ __align__(16) f16 sA[3 * 2 * 32 * 32];   // 12 KiB
    __shared__ __align__(16) f16 sW[3 * 2 * 48 * 32];   // 18 KiB
    int tid = threadIdx.x;
    int lane = tid & 63;
    int mfrag = tid >> 6;   // wave 0/1
    int c0 = blockIdx.x * 16;
    int m0 = blockIdx.y * 32;

    if (hsq_zero && blockIdx.x == 0 && tid < 32) hsq_zero[m0 + tid] = 0.0f;
    if (amax_zero && blockIdx.x == 0 && tid < 32) amax_zero[m0 + tid] = 0ull;

    f32x4 acc[3], accx[3], accy[3];
#pragma unroll
    for (int g = 0; g < 3; ++g) {
        acc[g] = (f32x4){0.f, 0.f, 0.f, 0.f};
        accx[g] = (f32x4){0.f, 0.f, 0.f, 0.f};
        accy[g] = (f32x4){0.f, 0.f, 0.f, 0.f};
    }

    gru_phase3(A0, A1, A2, Wi0, Wi1, Wi2, K1, m0, c0, tid, lane, mfrag,
               acc, accx, accy, sA, sW);

    float gi[3][4];
#pragma unroll
    for (int g = 0; g < 3; ++g)
#pragma unroll
        for (int r = 0; r < 4; ++r) {
            gi[g][r] = acc[g][r] + accx[g][r] * S1 + accy[g][r] * S2;
            acc[g][r] = 0.f; accx[g][r] = 0.f; accy[g][r] = 0.f;
        }

    gru_phase3(P0, P1, P2, Wh0, Wh1, Wh2, 256, m0, c0, tid, lane, mfrag,
               acc, accx, accy, sA, sW);

    gru_epilogue(acc, accx, accy, gi, bih, bhh, Hprevf, Hnewf, O0, O1, O2, hsq_acc,
                 m0, c0, lane, mfrag);
}

// ---------------- folded GRU0 (t>=1): A = [h1_prev, emb[sel]]; 128 thr ----------------
__global__ __launch_bounds__(128, 2) void gru_mfma3_f(
    const f16* __restrict__ H10, const f16* __restrict__ H11, const f16* __restrict__ H12,
    const f16* __restrict__ E0, const f16* __restrict__ E1, const f16* __restrict__ E2,
    const u64* __restrict__ amax,
    const f16* __restrict__ Wc0, const f16* __restrict__ Wc1, const f16* __restrict__ Wc2,
    const f16* __restrict__ P0, const f16* __restrict__ P1, const f16* __restrict__ P2,
    const f16* __restrict__ Wh0, const f16* __restrict__ Wh1, const f16* __restrict__ Wh2,
    const float* __restrict__ bihc, const float* __restrict__ bhh,
    const float* __restrict__ Hprevf,
    float* __restrict__ Hnewf,
    f16* __restrict__ O0, f16* __restrict__ O1, f16* __restrict__ O2,
    float* __restrict__ hsq_zero, float* __restrict__ traj_prev) {
    __shared__ __align__(16) f16 sA[3 * 2 * 32 * 32];
    __shared__ __align__(16) f16 sW[3 * 2 * 48 * 32];
    __shared__ unsigned sSel[32];
    int tid = threadIdx.x;
    int lane = tid & 63;
    int mfrag = tid >> 6;
    int c0 = blockIdx.x * 16;
    int m0 = blockIdx.y * 32;

    if (tid < 32) {
        unsigned selv = 0xFFFFFFFFu - (unsigned)(amax[m0 + tid] & 0xFFFFFFFFull);
        sSel[tid] = selv;
        if (blockIdx.x == 0) {
            traj_prev[m0 + tid] = (float)selv;
            if (hsq_zero) hsq_zero[m0 + tid] = 0.0f;
        }
    }
    __syncthreads();

    f32x4 acc[3], accx[3], accy[3];
#pragma unroll
    for (int g = 0; g < 3; ++g) {
        acc[g] = (f32x4){0.f, 0.f, 0.f, 0.f};
        accx[g] = (f32x4){0.f, 0.f, 0.f, 0.f};
        accy[g] = (f32x4){0.f, 0.f, 0.f, 0.f};
    }

    gru_phase3_f(H10, H11, H12, E0, E1, E2, sSel, Wc0, Wc1, Wc2,
                 m0, c0, tid, lane, mfrag, acc, accx, accy, sA, sW);

    float gi[3][4];
#pragma unroll
    for (int g = 0; g < 3; ++g)
#pragma unroll
        for (int r = 0; r < 4; ++r) {
            gi[g][r] = acc[g][r] + accx[g][r] * S1 + accy[g][r] * S2;
            acc[g][r] = 0.f; accx[g][r] = 0.f; accy[g][r] = 0.f;
        }

    gru_phase3(P0, P1, P2, Wh0, Wh1, Wh2, 256, m0, c0, tid, lane, mfrag,
               acc, accx, accy, sA, sW);

    gru_epilogue(acc, accx, accy, gi, bihc, bhh, Hprevf, Hnewf, O0, O1, O2, nullptr,
                 m0, c0, lane, mfrag);
}

// ---------------- MFMA scores + fused argmax; global_load_lds staging ------------------
__global__ __launch_bounds__(256, 2) void scores_mfma(
    const f16* __restrict__ Ahh, const f16* __restrict__ All,
    const f16* __restrict__ W1h, const f16* __restrict__ W1l,
    const f16* __restrict__ W2h, const f16* __restrict__ W2l,
    const float* __restrict__ hsq, const float* __restrict__ be,
    const float* __restrict__ osq, float* __restrict__ out,
    u64* __restrict__ amax) {
    __shared__ __align__(16) f16 sA[2 * 2 * 128 * 32];
    __shared__ __align__(16) f16 sB[4 * 2 * 64 * 32];
    int tid = threadIdx.x;
    int lane = tid & 63;
    int wave = tid >> 6;
    int wm = wave >> 1;
    int wn = wave & 1;
    int n0 = blockIdx.x * 64;
    int m0 = blockIdx.y * 128;

    f32x4 acc1[4][2], acc1x[4][2], acc2[4][2], acc2x[4][2];
#pragma unroll
    for (int i = 0; i < 4; ++i)
#pragma unroll
        for (int j = 0; j < 2; ++j) {
            acc1[i][j] = (f32x4){0.f, 0.f, 0.f, 0.f};
            acc1x[i][j] = (f32x4){0.f, 0.f, 0.f, 0.f};
            acc2[i][j] = (f32x4){0.f, 0.f, 0.f, 0.f};
            acc2x[i][j] = (f32x4){0.f, 0.f, 0.f, 0.f};
        }

    for (int k0 = 0; k0 < 256; k0 += 64) {
#pragma unroll
        for (int it = 0; it < 8; ++it) {
            int idx = tid + 256 * it;
            int half = idx >> 10;
            int rem = idx & 1023;
            int kslot = rem >> 9;
            int within = rem & 511;
            int r = within >> 2, slt = within & 3;
            const f16* src = (half ? All : Ahh)
                             + (size_t)(m0 + r) * 256 + k0 + kslot * 32 + SWZ(r, slt) * 8;
            GLDS(src, &sA[idx * 8]);
        }
#pragma unroll
        for (int it = 0; it < 8; ++it) {
            int idx = tid + 256 * it;
            int arr = idx >> 9;
            int rem = idx & 511;
            int kslot = rem >> 8;
            int within = rem & 255;
            int r = within >> 2, slt = within & 3;
            const f16* src = (arr == 0) ? W1h : (arr == 1) ? W1l : (arr == 2) ? W2h : W2l;
            int gn = n0 + r;
            if (gn >= NOPS) gn = 0;
            GLDS(src + (size_t)gn * 256 + k0 + kslot * 32 + SWZ(r, slt) * 8, &sB[idx * 8]);
        }
        __syncthreads();

#pragma unroll
        for (int kslot = 0; kslot < 2; ++kslot) {
            f16x8 ah[4], al[4];
#pragma unroll
            for (int fm = 0; fm < 4; ++fm) {
                int r = wm * 64 + fm * 16 + (lane & 15);
                int sl = SWZ(r, lane >> 4);
                ah[fm] = *(const f16x8*)&sA[kslot * 4096 + r * 32 + sl * 8];
                al[fm] = *(const f16x8*)&sA[8192 + kslot * 4096 + r * 32 + sl * 8];
            }
#pragma unroll
            for (int fn = 0; fn < 2; ++fn) {
                int r = wn * 32 + fn * 16 + (lane & 15);
                int sl = SWZ(r, lane >> 4);
                f16x8 b1h = *(const f16x8*)&sB[kslot * 2048 + r * 32 + sl * 8];
                f16x8 b1l = *(const f16x8*)&sB[4096 + kslot * 2048 + r * 32 + sl * 8];
                f16x8 b2h = *(const f16x8*)&sB[8192 + kslot * 2048 + r * 32 + sl * 8];
                f16x8 b2l = *(const f16x8*)&sB[12288 + kslot * 2048 + r * 32 + sl * 8];
#pragma unroll
                for (int fm = 0; fm < 4; ++fm) {
                    acc1[fm][fn]  = __builtin_amdgcn_mfma_f32_16x16x32_f16(ah[fm], b1h, acc1[fm][fn], 0, 0, 0);
                    acc1x[fm][fn] = __builtin_amdgcn_mfma_f32_16x16x32_f16(al[fm], b1h, acc1x[fm][fn], 0, 0, 0);
                    acc1x[fm][fn] = __builtin_amdgcn_mfma_f32_16x16x32_f16(ah[fm], b1l, acc1x[fm][fn], 0, 0, 0);
                    acc2[fm][fn]  = __builtin_amdgcn_mfma_f32_16x16x32_f16(ah[fm], b2h, acc2[fm][fn], 0, 0, 0);
                    acc2x[fm][fn] = __builtin_amdgcn_mfma_f32_16x16x32_f16(al[fm], b2h, acc2x[fm][fn], 0, 0, 0);
                    acc2x[fm][fn] = __builtin_amdgcn_mfma_f32_16x16x32_f16(ah[fm], b2l, acc2x[fm][fn], 0, 0, 0);
                }
            }
        }
        __syncthreads();
    }

    const float inv = 1.0f / 1024.0f;
    int nn[2]; float bev[2], osv[2]; bool okn[2];
#pragma unroll
    for (int fn = 0; fn < 2; ++fn) {
        nn[fn] = n0 + wn * 32 + fn * 16 + (lane & 15);
        okn[fn] = nn[fn] < NOPS;
        bev[fn] = okn[fn] ? be[nn[fn]] : 0.0f;
        osv[fn] = okn[fn] ? osq[nn[fn]] : 0.0f;
    }
#pragma unroll
    for (int fm = 0; fm < 4; ++fm) {
#pragma unroll
        for (int r = 0; r < 4; ++r) {
            int m = m0 + wm * 64 + fm * 16 + (lane >> 4) * 4 + r;
            float hs = hsq[m];
            u64 bestk = 0ull;
#pragma unroll
            for (int fn = 0; fn < 2; ++fn) {
                if (okn[fn]) {
                    float dot1 = acc1[fm][fn][r] + acc1x[fm][fn][r] * inv;
                    float dot2 = acc2[fm][fn][r] + acc2x[fm][fn][r] * inv;
                    float sc = (dot1 + bev[fn])
                             - 0.5f * sqrtf(fmaxf(hs + osv[fn] - 2.0f * dot2, 0.0f));
                    out[(size_t)m * NOPS + nn[fn]] = sc;
                    unsigned int u = __float_as_uint(sc);
                    unsigned int mono = (u & 0x80000000u) ? ~u : (u | 0x80000000u);
                    u64 key = ((u64)mono << 32) | (u64)(0xFFFFFFFFu - (unsigned)nn[fn]);
                    if (key > bestk) bestk = key;
                }
            }
#pragma unroll
            for (int off = 1; off < 16; off <<= 1) {
                u64 ok = __shfl_xor(bestk, off);
                if (ok > bestk) bestk = ok;
            }
            if ((lane & 15) == 0) atomicMax(amax + m, bestk);
        }
    }
}

// ---------------- final traj write ----------------
__global__ __launch_bounds__(256) void writetraj(const u64* __restrict__ amax,
                                                 float* __restrict__ traj) {
    int i = blockIdx.x * blockDim.x + threadIdx.x;
    if (i < B) {
        unsigned selv = 0xFFFFFFFFu - (unsigned)(amax[i] & 0xFFFFFFFFull);
        traj[i] = (float)selv;
    }
}

extern "C" void kernel_launch(void* const* d_in, const int* in_sizes, int n_in,
                              void* d_out, int out_size, void* d_ws, size_t ws_size,
                              hipStream_t stream) {
    const float* geo      = (const float*)d_in[0];
    const float* sem      = (const float*)d_in[1];
    const float* w_ih0    = (const float*)d_in[2];
    const float* w_hh0    = (const float*)d_in[3];
    const float* b_ih0    = (const float*)d_in[4];
    const float* b_hh0    = (const float*)d_in[5];
    const float* w_ih1    = (const float*)d_in[6];
    const float* w_hh1    = (const float*)d_in[7];
    const float* b_ih1    = (const float*)d_in[8];
    const float* b_hh1    = (const float*)d_in[9];
    const float* w_energy = (const float*)d_in[10];
    const float* b_energy = (const float*)d_in[11];
    const float* w_proj   = (const float*)d_in[12];
    const float* b_proj   = (const float*)d_in[13];
    const float* w_op     = (const float*)d_in[14];
    const float* op_emb   = (const float*)d_in[15];

    char* p = (char*)d_ws;
    auto alloc = [&](size_t bytes) { char* q = p; p += (bytes + 255) & ~255ULL; return q; };
    float* opp   = (float*)alloc((size_t)NOPS * 256 * 4);
    float* oppsq = (float*)alloc((size_t)NOPS * 4);
    float* hsq   = (float*)alloc((size_t)B * 4);
    u64*   amax  = (u64*)  alloc((size_t)B * 8);
    float* wcf   = (float*)alloc((size_t)768 * 512 * 4);
    float* bihc  = (float*)alloc((size_t)768 * 4);
    float *h0f[2], *h1f[2];
    f16 *h0c[2][3], *h1c[2][3];
    for (int i = 0; i < 2; ++i) {
        h0f[i] = (float*)alloc((size_t)B * H * 4);
        h1f[i] = (float*)alloc((size_t)B * H * 4);
        for (int j = 0; j < 3; ++j) {
            h0c[i][j] = (f16*)alloc((size_t)B * H * 2);
            h1c[i][j] = (f16*)alloc((size_t)B * H * 2);
        }
    }
    f16* x0 = (f16*)alloc((size_t)B * INDIM * 2);
    f16* x1 = (f16*)alloc((size_t)B * INDIM * 2);
    f16* x2 = (f16*)alloc((size_t)B * INDIM * 2);
    f16 *wi0[3], *wh0[3], *wi1[3], *wh1[3], *wc[3], *emb[3];
    for (int i = 0; i < 3; ++i) {
        wi0[i] = (f16*)alloc((size_t)768 * 320 * 2);
        wh0[i] = (f16*)alloc((size_t)768 * 256 * 2);
        wi1[i] = (f16*)alloc((size_t)768 * 256 * 2);
        wh1[i] = (f16*)alloc((size_t)768 * 256 * 2);
        wc[i]  = (f16*)alloc((size_t)768 * 512 * 2);
        emb[i] = (f16*)alloc((size_t)NOPS * 256 * 2);
    }
    f16* weh = (f16*)alloc((size_t)NOPS * 256 * 2);
    f16* wel = (f16*)alloc((size_t)NOPS * 256 * 2);
    f16* oph = (f16*)alloc((size_t)NOPS * 256 * 2);
    f16* opl = (f16*)alloc((size_t)NOPS * 256 * 2);

    float* out    = (float*)d_out;
    float* traj   = out;
    float* scores = out + (size_t)STEPS * B;

    init_kernel<<<dim3((B * INDIM + 255) / 256), dim3(256), 0, stream>>>(
        geo, sem, x0, x1, x2, h0f[0], h1f[0],
        h0c[0][0], h0c[0][1], h0c[0][2], h1c[0][0], h1c[0][1], h1c[0][2],
        hsq, amax);
    gemm_tn<<<dim3(256 / BN, (NOPS + BM - 1) / BM), dim3(256), 0, stream>>>(
        op_emb, w_op, nullptr, opp, NOPS, 256, 256);
    gemm_nn<<<dim3(512 / BN, 768 / BM), dim3(256), 0, stream>>>(w_ih0, w_proj, wcf, 768, 512, 320);
    rowdot_bias<<<dim3(192), dim3(256), 0, stream>>>(w_ih0, b_proj, b_ih0, bihc);
    cvt3_rows<<<dim3(192), dim3(256), 0, stream>>>(w_ih0, 768, 320, wi0[0], wi0[1], wi0[2]);
    cvt3_rows<<<dim3(192), dim3(256), 0, stream>>>(w_hh0, 768, 256, wh0[0], wh0[1], wh0[2]);
    cvt3_rows<<<dim3(192), dim3(256), 0, stream>>>(w_ih1, 768, 256, wi1[0], wi1[1], wi1[2]);
    cvt3_rows<<<dim3(192), dim3(256), 0, stream>>>(w_hh1, 768, 256, wh1[0], wh1[1], wh1[2]);
    cvt3_rows<<<dim3(192), dim3(256), 0, stream>>>(wcf, 768, 512, wc[0], wc[1], wc[2]);
    cvt3_rows<<<dim3((NOPS + 3) / 4), dim3(256), 0, stream>>>(op_emb, NOPS, 256, emb[0], emb[1], emb[2]);
    cvt_rows<<<dim3((NOPS + 3) / 4), dim3(256), 0, stream>>>(w_energy, NOPS, 256, weh, wel, nullptr);
    cvt_rows<<<dim3((NOPS + 3) / 4), dim3(256), 0, stream>>>(opp, NOPS, 256, oph, opl, oppsq);

    for (int t = 0; t < STEPS; ++t) {
        int pi = t & 1, po = pi ^ 1;

        if (t == 0) {
            gru_mfma3<<<dim3(H / 16, B / 32), dim3(128), 0, stream>>>(
                x0, x1, x2, INDIM, wi0[0], wi0[1], wi0[2],
                h0c[pi][0], h0c[pi][1], h0c[pi][2], wh0[0], wh0[1], wh0[2],
                b_ih0, b_hh0, h0f[pi], h0f[po], h0c[po][0], h0c[po][1], h0c[po][2],
                hsq, nullptr, nullptr);
        } else {
            gru_mfma3_f<<<dim3(H / 16, B / 32), dim3(128), 0, stream>>>(
                h1c[pi][0], h1c[pi][1], h1c[pi][2],
                emb[0], emb[1], emb[2], amax,
                wc[0], wc[1], wc[2],
                h0c[pi][0], h0c[pi][1], h0c[pi][2], wh0[0], wh0[1], wh0[2],
                bihc, b_hh0, h0f[pi], h0f[po], h0c[po][0], h0c[po][1], h0c[po][2],
                hsq, traj + (size_t)(t - 1) * B);
        }
        gru_mfma3<<<dim3(H / 16, B / 32), dim3(128), 0, stream>>>(
            h0c[po][0], h0c[po][1], h0c[po][2], 256, wi1[0], wi1[1], wi1[2],
            h1c[pi][0], h1c[pi][1], h1c[pi][2], wh1[0], wh1[1], wh1[2],
            b_ih1, b_hh1, h1f[pi], h1f[po], h1c[po][0], h1c[po][1], h1c[po][2],
            nullptr, hsq, amax);

        scores_mfma<<<dim3((NOPS + 63) / 64, B / 128), dim3(256), 0, stream>>>(
            h1c[po][0], h1c[po][1], weh, wel, oph, opl, hsq, b_energy, oppsq,
            scores + (size_t)t * B * NOPS, amax);
    }
    writetraj<<<dim3((B + 255) / 256), dim3(256), 0, stream>>>(amax, traj + (size_t)(STEPS - 1) * B);
}

// Round 12
// 1805.122 us; speedup vs baseline: 1.0589x; 1.0589x over previous
//
#include <hip/hip_runtime.h>
#include <math.h>

#define B 2048
#define H 256
#define INDIM 320
#define NOPS 1883
#define STEPS 20

typedef _Float16 f16;
typedef _Float16 f16x4 __attribute__((ext_vector_type(4)));
typedef _Float16 f16x8 __attribute__((ext_vector_type(8)));
typedef float f32x4 __attribute__((ext_vector_type(4)));
typedef unsigned long long u64;

// XOR swizzle: 4 16B-slots per 64B (32-f16) row; bijective involution per row.
#define SWZ(r, s) ((s) ^ ((r) & 3) ^ (((r) >> 2) & 1))

// direct global->LDS 16B copy (LDS dest must be linear in lane order)
#define GLDS(src, dst) __builtin_amdgcn_global_load_lds( \
    (__attribute__((address_space(1))) void*)(src), \
    (__attribute__((address_space(3))) void*)(dst), 16, 0, 0)

#define S1 (1.0f / 1024.0f)
#define S2 (1.0f / 1048576.0f)

__device__ __forceinline__ void split3(float f, f16& c0, f16& c1, f16& c2) {
    c0 = (f16)f;
    float r1 = f - (float)c0;
    c1 = (f16)(r1 * 1024.0f);
    float r2 = r1 - (float)c1 * S1;
    c2 = (f16)(r2 * 1048576.0f);
}

// ---------------- init ----------------
__global__ __launch_bounds__(256) void init_kernel(const float* __restrict__ geo,
                                                   const float* __restrict__ sem,
                                                   f16* __restrict__ x0, f16* __restrict__ x1,
                                                   f16* __restrict__ x2,
                                                   float* __restrict__ h0f, float* __restrict__ h1f,
                                                   f16* __restrict__ h0c0, f16* __restrict__ h0c1,
                                                   f16* __restrict__ h0c2,
                                                   f16* __restrict__ h1c0, f16* __restrict__ h1c1,
                                                   f16* __restrict__ h1c2,
                                                   float* __restrict__ hsq, u64* __restrict__ amax) {
    int i = blockIdx.x * blockDim.x + threadIdx.x;
    if (i < B * INDIM) {
        int b = i / INDIM, c = i % INDIM;
        float f = (c < 256) ? geo[b * 256 + c] : sem[b * 64 + (c - 256)];
        f16 a, bb, cc;
        split3(f, a, bb, cc);
        x0[i] = a; x1[i] = bb; x2[i] = cc;
    }
    if (i < B * H) {
        h0f[i] = 0.0f; h1f[i] = 0.0f;
        h0c0[i] = (f16)0.0f; h0c1[i] = (f16)0.0f; h0c2[i] = (f16)0.0f;
        h1c0[i] = (f16)0.0f; h1c1[i] = (f16)0.0f; h1c2[i] = (f16)0.0f;
    }
    if (i < B) { hsq[i] = 0.0f; amax[i] = 0ull; }
}

// ---------------- generic tiled GEMM C = A * B^T (opp precompute) ----------------
#define BM 64
#define BN 64
#define BK 16
__global__ __launch_bounds__(256) void gemm_tn(const float* __restrict__ A,
                                               const float* __restrict__ Bm,
                                               const float* __restrict__ bias,
                                               float* __restrict__ C,
                                               int M, int N, int K) {
    __shared__ float As[BK][BM];
    __shared__ float Bs[BK][BN];
    int tid = threadIdx.x;
    int bm0 = blockIdx.y * BM;
    int bn0 = blockIdx.x * BN;
    int tx = tid & 15, ty = tid >> 4;
    int lr = tid >> 2;
    int lk = (tid & 3) << 2;

    float acc[4][4];
#pragma unroll
    for (int i = 0; i < 4; ++i)
#pragma unroll
        for (int j = 0; j < 4; ++j) acc[i][j] = 0.0f;

    for (int k0 = 0; k0 < K; k0 += BK) {
        {
            int gr = bm0 + lr;
            float4 v = make_float4(0.f, 0.f, 0.f, 0.f);
            if (gr < M) v = *(const float4*)(A + (size_t)gr * K + k0 + lk);
            As[lk + 0][lr] = v.x; As[lk + 1][lr] = v.y;
            As[lk + 2][lr] = v.z; As[lk + 3][lr] = v.w;
        }
        {
            int gn = bn0 + lr;
            float4 v = make_float4(0.f, 0.f, 0.f, 0.f);
            if (gn < N) v = *(const float4*)(Bm + (size_t)gn * K + k0 + lk);
            Bs[lk + 0][lr] = v.x; Bs[lk + 1][lr] = v.y;
            Bs[lk + 2][lr] = v.z; Bs[lk + 3][lr] = v.w;
        }
        __syncthreads();
#pragma unroll
        for (int k = 0; k < BK; ++k) {
            float a[4], b[4];
#pragma unroll
            for (int i = 0; i < 4; ++i) a[i] = As[k][ty * 4 + i];
#pragma unroll
            for (int j = 0; j < 4; ++j) b[j] = Bs[k][tx * 4 + j];
#pragma unroll
            for (int i = 0; i < 4; ++i)
#pragma unroll
                for (int j = 0; j < 4; ++j) acc[i][j] = fmaf(a[i], b[j], acc[i][j]);
        }
        __syncthreads();
    }
#pragma unroll
    for (int i = 0; i < 4; ++i) {
        int gr = bm0 + ty * 4 + i;
        if (gr >= M) continue;
#pragma unroll
        for (int j = 0; j < 4; ++j) {
            int gc = bn0 + tx * 4 + j;
            if (gc < N) C[(size_t)gr * N + gc] = acc[i][j] + (bias ? bias[gc] : 0.0f);
        }
    }
}

// ---------------- tiled GEMM C = A * B — Wc precompute ----------------
__global__ __launch_bounds__(256) void gemm_nn(const float* __restrict__ A,
                                               const float* __restrict__ Bm,
                                               float* __restrict__ C,
                                               int M, int N, int K) {
    __shared__ float As[BK][BM];
    __shared__ float Bs[BK][BN];
    int tid = threadIdx.x;
    int bm0 = blockIdx.y * BM;
    int bn0 = blockIdx.x * BN;
    int tx = tid & 15, ty = tid >> 4;
    int lr = tid >> 2;
    int lk = (tid & 3) << 2;

    float acc[4][4];
#pragma unroll
    for (int i = 0; i < 4; ++i)
#pragma unroll
        for (int j = 0; j < 4; ++j) acc[i][j] = 0.0f;

    for (int k0 = 0; k0 < K; k0 += BK) {
        {
            int gr = bm0 + lr;
            float4 v = make_float4(0.f, 0.f, 0.f, 0.f);
            if (gr < M) v = *(const float4*)(A + (size_t)gr * K + k0 + lk);
            As[lk + 0][lr] = v.x; As[lk + 1][lr] = v.y;
            As[lk + 2][lr] = v.z; As[lk + 3][lr] = v.w;
        }
        {
            int kk = tid >> 4;
            int n4 = (tid & 15) << 2;
            float4 v = *(const float4*)(Bm + (size_t)(k0 + kk) * N + bn0 + n4);
            Bs[kk][n4 + 0] = v.x; Bs[kk][n4 + 1] = v.y;
            Bs[kk][n4 + 2] = v.z; Bs[kk][n4 + 3] = v.w;
        }
        __syncthreads();
#pragma unroll
        for (int k = 0; k < BK; ++k) {
            float a[4], b[4];
#pragma unroll
            for (int i = 0; i < 4; ++i) a[i] = As[k][ty * 4 + i];
#pragma unroll
            for (int j = 0; j < 4; ++j) b[j] = Bs[k][tx * 4 + j];
#pragma unroll
            for (int i = 0; i < 4; ++i)
#pragma unroll
                for (int j = 0; j < 4; ++j) acc[i][j] = fmaf(a[i], b[j], acc[i][j]);
        }
        __syncthreads();
    }
#pragma unroll
    for (int i = 0; i < 4; ++i) {
        int gr = bm0 + ty * 4 + i;
        if (gr >= M) continue;
#pragma unroll
        for (int j = 0; j < 4; ++j) {
            int gc = bn0 + tx * 4 + j;
            if (gc < N) C[(size_t)gr * N + gc] = acc[i][j];
        }
    }
}

// ---------------- bihc[g] = b_ih0[g] + dot(Wi0[g,:320], bp) ----------------
__global__ __launch_bounds__(256) void rowdot_bias(const float* __restrict__ A,
                                                   const float* __restrict__ v,
                                                   const float* __restrict__ b0,
                                                   float* __restrict__ outb) {
    int row = blockIdx.x * 4 + (threadIdx.x >> 6);
    int lane = threadIdx.x & 63;
    if (row >= 768) return;
    float s = 0.0f;
    for (int j = lane; j < 320; j += 64) s = fmaf(A[(size_t)row * 320 + j], v[j], s);
#pragma unroll
    for (int off = 32; off > 0; off >>= 1) s += __shfl_down(s, off);
    if (lane == 0) outb[row] = b0[row] + s;
}

// ---------------- cvt device bodies ----------------
__device__ __forceinline__ void cvt2_dev(const float* __restrict__ A, int rows, int cols,
                                         f16* __restrict__ hi, f16* __restrict__ lo,
                                         float* __restrict__ sq, int blk) {
    int row = blk * 4 + (threadIdx.x >> 6);
    int lane = threadIdx.x & 63;
    if (row >= rows) return;
    const float* src = A + (size_t)row * cols;
    float s = 0.0f;
    for (int c0 = 0; c0 < cols; c0 += 256) {
        int idx = c0 + lane * 4;
        if (idx < cols) {
            float4 v = *(const float4*)(src + idx);
            float vv[4] = {v.x, v.y, v.z, v.w};
            f16x4 h, l;
#pragma unroll
            for (int j = 0; j < 4; ++j) {
                float f = vv[j];
                f16 hv = (f16)f;
                h[j] = hv;
                l[j] = (f16)((f - (float)hv) * 1024.0f);
                s = fmaf(f, f, s);
            }
            *(f16x4*)(hi + (size_t)row * cols + idx) = h;
            *(f16x4*)(lo + (size_t)row * cols + idx) = l;
        }
    }
    if (sq) {
#pragma unroll
        for (int off = 32; off > 0; off >>= 1) s += __shfl_down(s, off);
        if (lane == 0) sq[row] = s;
    }
}

__device__ __forceinline__ void cvt3_dev(const float* __restrict__ A, int rows, int cols,
                                         f16* __restrict__ o0, f16* __restrict__ o1,
                                         f16* __restrict__ o2, int blk) {
    int row = blk * 4 + (threadIdx.x >> 6);
    int lane = threadIdx.x & 63;
    if (row >= rows) return;
    const float* src = A + (size_t)row * cols;
    for (int c0 = 0; c0 < cols; c0 += 256) {
        int idx = c0 + lane * 4;
        if (idx < cols) {
            float4 v = *(const float4*)(src + idx);
            float vv[4] = {v.x, v.y, v.z, v.w};
            f16x4 a, b, c;
#pragma unroll
            for (int j = 0; j < 4; ++j) {
                f16 p, q, r;
                split3(vv[j], p, q, r);
                a[j] = p; b[j] = q; c[j] = r;
            }
            *(f16x4*)(o0 + (size_t)row * cols + idx) = a;
            *(f16x4*)(o1 + (size_t)row * cols + idx) = b;
            *(f16x4*)(o2 + (size_t)row * cols + idx) = c;
        }
    }
}

// ---------------- fused prologue conversion: all 8 cvt jobs in one launch -------------
// blocks: [0,192) wih0 | [192,384) whh0 | [384,576) wih1 | [576,768) whh1 |
//         [768,960) wcf | [960,1431) op_emb | [1431,1902) w_energy | [1902,2373) opp
__global__ __launch_bounds__(256) void cvt_all(
    const float* __restrict__ wih0, f16* a0, f16* a1, f16* a2,
    const float* __restrict__ whh0, f16* b0, f16* b1, f16* b2,
    const float* __restrict__ wih1, f16* c0, f16* c1, f16* c2,
    const float* __restrict__ whh1, f16* d0, f16* d1, f16* d2,
    const float* __restrict__ wcf,  f16* e0, f16* e1, f16* e2,
    const float* __restrict__ opemb, f16* f0, f16* f1, f16* f2,
    const float* __restrict__ wen,  f16* g0, f16* g1,
    const float* __restrict__ opp,  f16* h0, f16* h1, float* osq) {
    int b = blockIdx.x;
    if (b < 192)        cvt3_dev(wih0, 768, 320, a0, a1, a2, b);
    else if (b < 384)   cvt3_dev(whh0, 768, 256, b0, b1, b2, b - 192);
    else if (b < 576)   cvt3_dev(wih1, 768, 256, c0, c1, c2, b - 384);
    else if (b < 768)   cvt3_dev(whh1, 768, 256, d0, d1, d2, b - 576);
    else if (b < 960)   cvt3_dev(wcf, 768, 512, e0, e1, e2, b - 768);
    else if (b < 1431)  cvt3_dev(opemb, NOPS, 256, f0, f1, f2, b - 960);
    else if (b < 1902)  cvt2_dev(wen, NOPS, 256, g0, g1, nullptr, b - 1431);
    else                cvt2_dev(opp, NOPS, 256, h0, h1, osq, b - 1902);
}

// ---------------- MFMA inner, M=32 tile (2 mfrags x 2 hhalves, 4 waves) ----------------
__device__ __forceinline__ void gru_mfma_tile(
    const f16* sA, const f16* sW, int lane, int mfrag, int hhalf,
    f32x4* acc, f32x4* accx, f32x4* accy) {
#pragma unroll
    for (int kslot = 0; kslot < 2; ++kslot) {
        int ar = mfrag * 16 + (lane & 15);
        int asl = SWZ(ar, lane >> 4);
        f16x8 a0 = *(const f16x8*)&sA[kslot * 1024 + ar * 32 + asl * 8];
        f16x8 a1 = *(const f16x8*)&sA[2048 + kslot * 1024 + ar * 32 + asl * 8];
        f16x8 a2 = *(const f16x8*)&sA[4096 + kslot * 1024 + ar * 32 + asl * 8];
#pragma unroll
        for (int g = 0; g < 3; ++g) {
            int br_ = g * 32 + hhalf * 16 + (lane & 15);
            int bsl = SWZ(br_, lane >> 4);
            f16x8 b0 = *(const f16x8*)&sW[kslot * 3072 + br_ * 32 + bsl * 8];
            f16x8 b1 = *(const f16x8*)&sW[6144 + kslot * 3072 + br_ * 32 + bsl * 8];
            f16x8 b2 = *(const f16x8*)&sW[12288 + kslot * 3072 + br_ * 32 + bsl * 8];
            acc[g]  = __builtin_amdgcn_mfma_f32_16x16x32_f16(a0, b0, acc[g], 0, 0, 0);
            accx[g] = __builtin_amdgcn_mfma_f32_16x16x32_f16(a0, b1, accx[g], 0, 0, 0);
            accx[g] = __builtin_amdgcn_mfma_f32_16x16x32_f16(a1, b0, accx[g], 0, 0, 0);
            accy[g] = __builtin_amdgcn_mfma_f32_16x16x32_f16(a0, b2, accy[g], 0, 0, 0);
            accy[g] = __builtin_amdgcn_mfma_f32_16x16x32_f16(a1, b1, accy[g], 0, 0, 0);
            accy[g] = __builtin_amdgcn_mfma_f32_16x16x32_f16(a2, b0, accy[g], 0, 0, 0);
        }
    }
}

// ---------------- triple-split GRU k-phase; M=32, 256 thr, global_load_lds -------------
__device__ __forceinline__ void gru_phase3(
    const f16* __restrict__ A0, const f16* __restrict__ A1, const f16* __restrict__ A2,
    const f16* __restrict__ W0, const f16* __restrict__ W1, const f16* __restrict__ W2,
    int K, int m0, int c0, int tid, int lane, int mfrag, int hhalf,
    f32x4* acc, f32x4* accx, f32x4* accy, f16* sA, f16* sW) {
    for (int k0 = 0; k0 < K; k0 += 64) {
#pragma unroll
        for (int it = 0; it < 3; ++it) {
            int idx = tid + 256 * it;
            int third = idx >> 8, rem = idx & 255;
            int kslot = rem >> 7, within = rem & 127;
            int row = within >> 2, slot = within & 3;
            const f16* src = (third == 0 ? A0 : third == 1 ? A1 : A2)
                             + (size_t)(m0 + row) * K + k0 + kslot * 32 + SWZ(row, slot) * 8;
            GLDS(src, &sA[idx * 8]);
        }
#pragma unroll
        for (int it = 0; it < 9; ++it) {
            int idx = tid + 256 * it;
            int third = idx / 768;
            int rem = idx - third * 768;
            int kslot = rem / 384;
            int within = rem - kslot * 384;
            int row = within >> 2, slot = within & 3;
            int wr = ((row >> 5) << 8) + c0 + (row & 31);
            const f16* src = (third == 0 ? W0 : third == 1 ? W1 : W2)
                             + (size_t)wr * K + k0 + kslot * 32 + SWZ(row, slot) * 8;
            GLDS(src, &sW[idx * 8]);
        }
        __syncthreads();
        gru_mfma_tile(sA, sW, lane, mfrag, hhalf, acc, accx, accy);
        __syncthreads();
    }
}

// A = concat(H1[256], emb[sel][256]); W stride 512. M=32, global_load_lds staging.
__device__ __forceinline__ void gru_phase3_f(
    const f16* __restrict__ H10, const f16* __restrict__ H11, const f16* __restrict__ H12,
    const f16* __restrict__ E0, const f16* __restrict__ E1, const f16* __restrict__ E2,
    const unsigned* __restrict__ sSel,
    const f16* __restrict__ W0, const f16* __restrict__ W1, const f16* __restrict__ W2,
    int m0, int c0, int tid, int lane, int mfrag, int hhalf,
    f32x4* acc, f32x4* accx, f32x4* accy, f16* sA, f16* sW) {
    for (int k0 = 0; k0 < 512; k0 += 64) {
#pragma unroll
        for (int it = 0; it < 3; ++it) {
            int idx = tid + 256 * it;
            int third = idx >> 8, rem = idx & 255;
            int kslot = rem >> 7, within = rem & 127;
            int row = within >> 2, slot = within & 3;
            int keff = k0 + kslot * 32;
            const f16* src;
            if (keff < 256) {
                const f16* base = (third == 0 ? H10 : third == 1 ? H11 : H12);
                src = base + (size_t)(m0 + row) * 256 + keff + SWZ(row, slot) * 8;
            } else {
                const f16* base = (third == 0 ? E0 : third == 1 ? E1 : E2);
                src = base + (size_t)sSel[row] * 256 + (keff - 256) + SWZ(row, slot) * 8;
            }
            GLDS(src, &sA[idx * 8]);
        }
#pragma unroll
        for (int it = 0; it < 9; ++it) {
            int idx = tid + 256 * it;
            int third = idx / 768;
            int rem = idx - third * 768;
            int kslot = rem / 384;
            int within = rem - kslot * 384;
            int row = within >> 2, slot = within & 3;
            int wr = ((row >> 5) << 8) + c0 + (row & 31);
            const f16* src = (third == 0 ? W0 : third == 1 ? W1 : W2)
                             + (size_t)wr * 512 + k0 + kslot * 32 + SWZ(row, slot) * 8;
            GLDS(src, &sW[idx * 8]);
        }
        __syncthreads();
        gru_mfma_tile(sA, sW, lane, mfrag, hhalf, acc, accx, accy);
        __syncthreads();
    }
}

// ---------------- GRU epilogue (M=32) ----------------
__device__ __forceinline__ void gru_epilogue(
    f32x4* acc, f32x4* accx, f32x4* accy, float gi[3][4],
    const float* bih, const float* bhh,
    const float* Hprevf, float* Hnewf,
    f16* O0, f16* O1, f16* O2, float* hsq_acc,
    int m0, int c0, int lane, int mfrag, int hhalf) {
    int c = c0 + hhalf * 16 + (lane & 15);
    float br = bih[c] + bhh[c];
    float bz = bih[256 + c] + bhh[256 + c];
    float bni = bih[512 + c];
    float bnh = bhh[512 + c];
#pragma unroll
    for (int r = 0; r < 4; ++r) {
        int row = m0 + mfrag * 16 + (lane >> 4) * 4 + r;
        float gh_r = acc[0][r] + accx[0][r] * S1 + accy[0][r] * S2;
        float gh_z = acc[1][r] + accx[1][r] * S1 + accy[1][r] * S2;
        float gh_n = acc[2][r] + accx[2][r] * S1 + accy[2][r] * S2;
        float rg = 1.0f / (1.0f + expf(-(gi[0][r] + gh_r + br)));
        float zg = 1.0f / (1.0f + expf(-(gi[1][r] + gh_z + bz)));
        float ng = tanhf(gi[2][r] + bni + rg * (gh_n + bnh));
        float hp = Hprevf[(size_t)row * 256 + c];
        float o = (1.0f - zg) * ng + zg * hp;
        Hnewf[(size_t)row * 256 + c] = o;
        f16 q0, q1, q2;
        split3(o, q0, q1, q2);
        O0[(size_t)row * 256 + c] = q0;
        O1[(size_t)row * 256 + c] = q1;
        O2[(size_t)row * 256 + c] = q2;
        if (hsq_acc) {
            float sq = o * o;
#pragma unroll
            for (int off = 1; off < 16; off <<= 1) sq += __shfl_xor(sq, off);
            if ((lane & 15) == 0) atomicAdd(hsq_acc + row, sq);
        }
    }
}

// ---------------- GRU layer (generic A; t=0 gru0, all gru1). M=32, 2 blocks/CU --------
__global__ __launch_bounds__(256, 2) void gru_mfma3(
    const f16* __restrict__ A0, const f16* __restrict__ A1, const f16* __restrict__ A2, int K1,
    const f16* __restrict__ Wi0, const f16* __restrict__ Wi1, const f16* __restrict__ Wi2,
    const f16* __restrict__ P0, const f16* __restrict__ P1, const f16* __restrict__ P2,
    const f16* __restrict__ Wh0, const f16* __restrict__ Wh1, const f16* __restrict__ Wh2,
    const float* __restrict__ bih, const float* __restrict__ bhh,
    const float* __restrict__ Hprevf,
    float* __restrict__ Hnewf,
    f16* __restrict__ O0, f16* __restrict__ O1, f16* __restrict__ O2,
    float* __restrict__ hsq_zero, float* __restrict__ hsq_acc,
    u64* __restrict__ amax_zero) {
    __shared__ __align__(16) f16 sA[3 * 2 * 32 * 32];   // 12 KiB
    __shared__ __align__(16) f16 sW[3 * 2 * 96 * 32];   // 36 KiB
    int tid = threadIdx.x;
    int lane = tid & 63;
    int wave = tid >> 6;
    int mfrag = wave & 1;
    int hhalf = wave >> 1;
    int c0 = blockIdx.x * 32;
    int m0 = blockIdx.y * 32;

    if (hsq_zero && blockIdx.x == 0 && tid < 32) hsq_zero[m0 + tid] = 0.0f;
    if (amax_zero && blockIdx.x == 0 && tid < 32) amax_zero[m0 + tid] = 0ull;

    f32x4 acc[3], accx[3], accy[3];
#pragma unroll
    for (int g = 0; g < 3; ++g) {
        acc[g] = (f32x4){0.f, 0.f, 0.f, 0.f};
        accx[g] = (f32x4){0.f, 0.f, 0.f, 0.f};
        accy[g] = (f32x4){0.f, 0.f, 0.f, 0.f};
    }

    gru_phase3(A0, A1, A2, Wi0, Wi1, Wi2, K1, m0, c0, tid, lane, mfrag, hhalf,
               acc, accx, accy, sA, sW);

    float gi[3][4];
#pragma unroll
    for (int g = 0; g < 3; ++g)
#pragma unroll
        for (int r = 0; r < 4; ++r) {
            gi[g][r] = acc[g][r] + accx[g][r] * S1 + accy[g][r] * S2;
            acc[g][r] = 0.f; accx[g][r] = 0.f; accy[g][r] = 0.f;
        }

    gru_phase3(P0, P1, P2, Wh0, Wh1, Wh2, 256, m0, c0, tid, lane, mfrag, hhalf,
               acc, accx, accy, sA, sW);

    gru_epilogue(acc, accx, accy, gi, bih, bhh, Hprevf, Hnewf, O0, O1, O2, hsq_acc,
                 m0, c0, lane, mfrag, hhalf);
}

// ---------------- folded GRU0 (t>=1): A = [h1_prev, emb[sel]]; M=32, 2 blocks/CU ------
__global__ __launch_bounds__(256, 2) void gru_mfma3_f(
    const f16* __restrict__ H10, const f16* __restrict__ H11, const f16* __restrict__ H12,
    const f16* __restrict__ E0, const f16* __restrict__ E1, const f16* __restrict__ E2,
    const u64* __restrict__ amax,
    const f16* __restrict__ Wc0, const f16* __restrict__ Wc1, const f16* __restrict__ Wc2,
    const f16* __restrict__ P0, const f16* __restrict__ P1, const f16* __restrict__ P2,
    const f16* __restrict__ Wh0, const f16* __restrict__ Wh1, const f16* __restrict__ Wh2,
    const float* __restrict__ bihc, const float* __restrict__ bhh,
    const float* __restrict__ Hprevf,
    float* __restrict__ Hnewf,
    f16* __restrict__ O0, f16* __restrict__ O1, f16* __restrict__ O2,
    float* __restrict__ hsq_zero, float* __restrict__ traj_prev) {
    __shared__ __align__(16) f16 sA[3 * 2 * 32 * 32];
    __shared__ __align__(16) f16 sW[3 * 2 * 96 * 32];
    __shared__ unsigned sSel[32];
    int tid = threadIdx.x;
    int lane = tid & 63;
    int wave = tid >> 6;
    int mfrag = wave & 1;
    int hhalf = wave >> 1;
    int c0 = blockIdx.x * 32;
    int m0 = blockIdx.y * 32;

    if (tid < 32) {
        unsigned selv = 0xFFFFFFFFu - (unsigned)(amax[m0 + tid] & 0xFFFFFFFFull);
        sSel[tid] = selv;
        if (blockIdx.x == 0) {
            traj_prev[m0 + tid] = (float)selv;
            if (hsq_zero) hsq_zero[m0 + tid] = 0.0f;
        }
    }
    __syncthreads();

    f32x4 acc[3], accx[3], accy[3];
#pragma unroll
    for (int g = 0; g < 3; ++g) {
        acc[g] = (f32x4){0.f, 0.f, 0.f, 0.f};
        accx[g] = (f32x4){0.f, 0.f, 0.f, 0.f};
        accy[g] = (f32x4){0.f, 0.f, 0.f, 0.f};
    }

    gru_phase3_f(H10, H11, H12, E0, E1, E2, sSel, Wc0, Wc1, Wc2,
                 m0, c0, tid, lane, mfrag, hhalf, acc, accx, accy, sA, sW);

    float gi[3][4];
#pragma unroll
    for (int g = 0; g < 3; ++g)
#pragma unroll
        for (int r = 0; r < 4; ++r) {
            gi[g][r] = acc[g][r] + accx[g][r] * S1 + accy[g][r] * S2;
            acc[g][r] = 0.f; accx[g][r] = 0.f; accy[g][r] = 0.f;
        }

    gru_phase3(P0, P1, P2, Wh0, Wh1, Wh2, 256, m0, c0, tid, lane, mfrag, hhalf,
               acc, accx, accy, sA, sW);

    gru_epilogue(acc, accx, accy, gi, bihc, bhh, Hprevf, Hnewf, O0, O1, O2, nullptr,
                 m0, c0, lane, mfrag, hhalf);
}

// ---------------- MFMA scores + fused argmax; gload_lds + XCD-chunked tile map --------
__global__ __launch_bounds__(256, 2) void scores_mfma(
    const f16* __restrict__ Ahh, const f16* __restrict__ All,
    const f16* __restrict__ W1h, const f16* __restrict__ W1l,
    const f16* __restrict__ W2h, const f16* __restrict__ W2l,
    const float* __restrict__ hsq, const float* __restrict__ be,
    const float* __restrict__ osq, float* __restrict__ out,
    u64* __restrict__ amax) {
    __shared__ __align__(16) f16 sA[2 * 2 * 128 * 32];
    __shared__ __align__(16) f16 sB[4 * 2 * 64 * 32];
    int tid = threadIdx.x;
    int lane = tid & 63;
    int wave = tid >> 6;
    int wm = wave >> 1;
    int wn = wave & 1;
    // XCD-aware chunked remap: 480 blocks = 8 XCDs x 60; each XCD gets 2 full m-rows
    // (all n) so its B-panel (~3.85 MB) stays resident in its 4 MB L2.
    int flat = blockIdx.y * 30 + blockIdx.x;
    int swz = (flat & 7) * 60 + (flat >> 3);
    int n0 = (swz % 30) * 64;
    int m0 = (swz / 30) * 128;

    f32x4 acc1[4][2], acc1x[4][2], acc2[4][2], acc2x[4][2];
#pragma unroll
    for (int i = 0; i < 4; ++i)
#pragma unroll
        for (int j = 0; j < 2; ++j) {
            acc1[i][j] = (f32x4){0.f, 0.f, 0.f, 0.f};
            acc1x[i][j] = (f32x4){0.f, 0.f, 0.f, 0.f};
            acc2[i][j] = (f32x4){0.f, 0.f, 0.f, 0.f};
            acc2x[i][j] = (f32x4){0.f, 0.f, 0.f, 0.f};
        }

    for (int k0 = 0; k0 < 256; k0 += 64) {
#pragma unroll
        for (int it = 0; it < 8; ++it) {
            int idx = tid + 256 * it;
            int half = idx >> 10;
            int rem = idx & 1023;
            int kslot = rem >> 9;
            int within = rem & 511;
            int r = within >> 2, slt = within & 3;
            const f16* src = (half ? All : Ahh)
                             + (size_t)(m0 + r) * 256 + k0 + kslot * 32 + SWZ(r, slt) * 8;
            GLDS(src, &sA[idx * 8]);
        }
#pragma unroll
        for (int it = 0; it < 8; ++it) {
            int idx = tid + 256 * it;
            int arr = idx >> 9;
            int rem = idx & 511;
            int kslot = rem >> 8;
            int within = rem & 255;
            int r = within >> 2, slt = within & 3;
            const f16* src = (arr == 0) ? W1h : (arr == 1) ? W1l : (arr == 2) ? W2h : W2l;
            int gn = n0 + r;
            if (gn >= NOPS) gn = 0;
            GLDS(src + (size_t)gn * 256 + k0 + kslot * 32 + SWZ(r, slt) * 8, &sB[idx * 8]);
        }
        __syncthreads();

#pragma unroll
        for (int kslot = 0; kslot < 2; ++kslot) {
            f16x8 ah[4], al[4];
#pragma unroll
            for (int fm = 0; fm < 4; ++fm) {
                int r = wm * 64 + fm * 16 + (lane & 15);
                int sl = SWZ(r, lane >> 4);
                ah[fm] = *(const f16x8*)&sA[kslot * 4096 + r * 32 + sl * 8];
                al[fm] = *(const f16x8*)&sA[8192 + kslot * 4096 + r * 32 + sl * 8];
            }
#pragma unroll
            for (int fn = 0; fn < 2; ++fn) {
                int r = wn * 32 + fn * 16 + (lane & 15);
                int sl = SWZ(r, lane >> 4);
                f16x8 b1h = *(const f16x8*)&sB[kslot * 2048 + r * 32 + sl * 8];
                f16x8 b1l = *(const f16x8*)&sB[4096 + kslot * 2048 + r * 32 + sl * 8];
                f16x8 b2h = *(const f16x8*)&sB[8192 + kslot * 2048 + r * 32 + sl * 8];
                f16x8 b2l = *(const f16x8*)&sB[12288 + kslot * 2048 + r * 32 + sl * 8];
#pragma unroll
                for (int fm = 0; fm < 4; ++fm) {
                    acc1[fm][fn]  = __builtin_amdgcn_mfma_f32_16x16x32_f16(ah[fm], b1h, acc1[fm][fn], 0, 0, 0);
                    acc1x[fm][fn] = __builtin_amdgcn_mfma_f32_16x16x32_f16(al[fm], b1h, acc1x[fm][fn], 0, 0, 0);
                    acc1x[fm][fn] = __builtin_amdgcn_mfma_f32_16x16x32_f16(ah[fm], b1l, acc1x[fm][fn], 0, 0, 0);
                    acc2[fm][fn]  = __builtin_amdgcn_mfma_f32_16x16x32_f16(ah[fm], b2h, acc2[fm][fn], 0, 0, 0);
                    acc2x[fm][fn] = __builtin_amdgcn_mfma_f32_16x16x32_f16(al[fm], b2h, acc2x[fm][fn], 0, 0, 0);
                    acc2x[fm][fn] = __builtin_amdgcn_mfma_f32_16x16x32_f16(ah[fm], b2l, acc2x[fm][fn], 0, 0, 0);
                }
            }
        }
        __syncthreads();
    }

    const float inv = 1.0f / 1024.0f;
    int nn[2]; float bev[2], osv[2]; bool okn[2];
#pragma unroll
    for (int fn = 0; fn < 2; ++fn) {
        nn[fn] = n0 + wn * 32 + fn * 16 + (lane & 15);
        okn[fn] = nn[fn] < NOPS;
        bev[fn] = okn[fn] ? be[nn[fn]] : 0.0f;
        osv[fn] = okn[fn] ? osq[nn[fn]] : 0.0f;
    }
#pragma unroll
    for (int fm = 0; fm < 4; ++fm) {
#pragma unroll
        for (int r = 0; r < 4; ++r) {
            int m = m0 + wm * 64 + fm * 16 + (lane >> 4) * 4 + r;
            float hs = hsq[m];
            u64 bestk = 0ull;
#pragma unroll
            for (int fn = 0; fn < 2; ++fn) {
                if (okn[fn]) {
                    float dot1 = acc1[fm][fn][r] + acc1x[fm][fn][r] * inv;
                    float dot2 = acc2[fm][fn][r] + acc2x[fm][fn][r] * inv;
                    float sc = (dot1 + bev[fn])
                             - 0.5f * sqrtf(fmaxf(hs + osv[fn] - 2.0f * dot2, 0.0f));
                    out[(size_t)m * NOPS + nn[fn]] = sc;
                    unsigned int u = __float_as_uint(sc);
                    unsigned int mono = (u & 0x80000000u) ? ~u : (u | 0x80000000u);
                    u64 key = ((u64)mono << 32) | (u64)(0xFFFFFFFFu - (unsigned)nn[fn]);
                    if (key > bestk) bestk = key;
                }
            }
#pragma unroll
            for (int off = 1; off < 16; off <<= 1) {
                u64 ok = __shfl_xor(bestk, off);
                if (ok > bestk) bestk = ok;
            }
            if ((lane & 15) == 0) atomicMax(amax + m, bestk);
        }
    }
}

// ---------------- final traj write ----------------
__global__ __launch_bounds__(256) void writetraj(const u64* __restrict__ amax,
                                                 float* __restrict__ traj) {
    int i = blockIdx.x * blockDim.x + threadIdx.x;
    if (i < B) {
        unsigned selv = 0xFFFFFFFFu - (unsigned)(amax[i] & 0xFFFFFFFFull);
        traj[i] = (float)selv;
    }
}

extern "C" void kernel_launch(void* const* d_in, const int* in_sizes, int n_in,
                              void* d_out, int out_size, void* d_ws, size_t ws_size,
                              hipStream_t stream) {
    const float* geo      = (const float*)d_in[0];
    const float* sem      = (const float*)d_in[1];
    const float* w_ih0    = (const float*)d_in[2];
    const float* w_hh0    = (const float*)d_in[3];
    const float* b_ih0    = (const float*)d_in[4];
    const float* b_hh0    = (const float*)d_in[5];
    const float* w_ih1    = (const float*)d_in[6];
    const float* w_hh1    = (const float*)d_in[7];
    const float* b_ih1    = (const float*)d_in[8];
    const float* b_hh1    = (const float*)d_in[9];
    const float* w_energy = (const float*)d_in[10];
    const float* b_energy = (const float*)d_in[11];
    const float* w_proj   = (const float*)d_in[12];
    const float* b_proj   = (const float*)d_in[13];
    const float* w_op     = (const float*)d_in[14];
    const float* op_emb   = (const float*)d_in[15];

    char* p = (char*)d_ws;
    auto alloc = [&](size_t bytes) { char* q = p; p += (bytes + 255) & ~255ULL; return q; };
    float* opp   = (float*)alloc((size_t)NOPS * 256 * 4);
    float* oppsq = (float*)alloc((size_t)NOPS * 4);
    float* hsq   = (float*)alloc((size_t)B * 4);
    u64*   amax  = (u64*)  alloc((size_t)B * 8);
    float* wcf   = (float*)alloc((size_t)768 * 512 * 4);
    float* bihc  = (float*)alloc((size_t)768 * 4);
    float *h0f[2], *h1f[2];
    f16 *h0c[2][3], *h1c[2][3];
    for (int i = 0; i < 2; ++i) {
        h0f[i] = (float*)alloc((size_t)B * H * 4);
        h1f[i] = (float*)alloc((size_t)B * H * 4);
        for (int j = 0; j < 3; ++j) {
            h0c[i][j] = (f16*)alloc((size_t)B * H * 2);
            h1c[i][j] = (f16*)alloc((size_t)B * H * 2);
        }
    }
    f16* x0 = (f16*)alloc((size_t)B * INDIM * 2);
    f16* x1 = (f16*)alloc((size_t)B * INDIM * 2);
    f16* x2 = (f16*)alloc((size_t)B * INDIM * 2);
    f16 *wi0[3], *wh0[3], *wi1[3], *wh1[3], *wc[3], *emb[3];
    for (int i = 0; i < 3; ++i) {
        wi0[i] = (f16*)alloc((size_t)768 * 320 * 2);
        wh0[i] = (f16*)alloc((size_t)768 * 256 * 2);
        wi1[i] = (f16*)alloc((size_t)768 * 256 * 2);
        wh1[i] = (f16*)alloc((size_t)768 * 256 * 2);
        wc[i]  = (f16*)alloc((size_t)768 * 512 * 2);
        emb[i] = (f16*)alloc((size_t)NOPS * 256 * 2);
    }
    f16* weh = (f16*)alloc((size_t)NOPS * 256 * 2);
    f16* wel = (f16*)alloc((size_t)NOPS * 256 * 2);
    f16* oph = (f16*)alloc((size_t)NOPS * 256 * 2);
    f16* opl = (f16*)alloc((size_t)NOPS * 256 * 2);

    float* out    = (float*)d_out;
    float* traj   = out;
    float* scores = out + (size_t)STEPS * B;

    init_kernel<<<dim3((B * INDIM + 255) / 256), dim3(256), 0, stream>>>(
        geo, sem, x0, x1, x2, h0f[0], h1f[0],
        h0c[0][0], h0c[0][1], h0c[0][2], h1c[0][0], h1c[0][1], h1c[0][2],
        hsq, amax);
    gemm_tn<<<dim3(256 / BN, (NOPS + BM - 1) / BM), dim3(256), 0, stream>>>(
        op_emb, w_op, nullptr, opp, NOPS, 256, 256);
    gemm_nn<<<dim3(512 / BN, 768 / BM), dim3(256), 0, stream>>>(w_ih0, w_proj, wcf, 768, 512, 320);
    rowdot_bias<<<dim3(192), dim3(256), 0, stream>>>(w_ih0, b_proj, b_ih0, bihc);
    // all 8 fp16 split conversions fused into one launch (saves 7 dispatch gaps)
    cvt_all<<<dim3(2373), dim3(256), 0, stream>>>(
        w_ih0, wi0[0], wi0[1], wi0[2],
        w_hh0, wh0[0], wh0[1], wh0[2],
        w_ih1, wi1[0], wi1[1], wi1[2],
        w_hh1, wh1[0], wh1[1], wh1[2],
        wcf,   wc[0],  wc[1],  wc[2],
        op_emb, emb[0], emb[1], emb[2],
        w_energy, weh, wel,
        opp, oph, opl, oppsq);

    for (int t = 0; t < STEPS; ++t) {
        int pi = t & 1, po = pi ^ 1;

        if (t == 0) {
            gru_mfma3<<<dim3(H / 32, B / 32), dim3(256), 0, stream>>>(
                x0, x1, x2, INDIM, wi0[0], wi0[1], wi0[2],
                h0c[pi][0], h0c[pi][1], h0c[pi][2], wh0[0], wh0[1], wh0[2],
                b_ih0, b_hh0, h0f[pi], h0f[po], h0c[po][0], h0c[po][1], h0c[po][2],
                hsq, nullptr, nullptr);
        } else {
            gru_mfma3_f<<<dim3(H / 32, B / 32), dim3(256), 0, stream>>>(
                h1c[pi][0], h1c[pi][1], h1c[pi][2],
                emb[0], emb[1], emb[2], amax,
                wc[0], wc[1], wc[2],
                h0c[pi][0], h0c[pi][1], h0c[pi][2], wh0[0], wh0[1], wh0[2],
                bihc, b_hh0, h0f[pi], h0f[po], h0c[po][0], h0c[po][1], h0c[po][2],
                hsq, traj + (size_t)(t - 1) * B);
        }
        gru_mfma3<<<dim3(H / 32, B / 32), dim3(256), 0, stream>>>(
            h0c[po][0], h0c[po][1], h0c[po][2], 256, wi1[0], wi1[1], wi1[2],
            h1c[pi][0], h1c[pi][1], h1c[pi][2], wh1[0], wh1[1], wh1[2],
            b_ih1, b_hh1, h1f[pi], h1f[po], h1c[po][0], h1c[po][1], h1c[po][2],
            nullptr, hsq, amax);

        scores_mfma<<<dim3((NOPS + 63) / 64, B / 128), dim3(256), 0, stream>>>(
            h1c[po][0], h1c[po][1], weh, wel, oph, opl, hsq, b_energy, oppsq,
            scores + (size_t)t * B * NOPS, amax);
    }
    writetraj<<<dim3((B + 255) / 256), dim3(256), 0, stream>>>(amax, traj + (size_t)(STEPS - 1) * B);
}